// Round 2
// baseline (502.805 us; speedup 1.0000x reference)
//
#include <hip/hip_runtime.h>

typedef __bf16 bf16;
typedef __bf16 bf16x4 __attribute__((ext_vector_type(4)));
typedef __bf16 bf16x8 __attribute__((ext_vector_type(8)));
typedef float  f32x2  __attribute__((ext_vector_type(2)));
typedef float  f32x4  __attribute__((ext_vector_type(4)));

#define NJ 75
#define NH 256
#define LN_EPS 1e-5f
#define A_S  104   // A_lds stride (bf16): 96 cols + pad, 16B-mult, 2-way banks
#define XT_S 104   // x_t stride
#define HS_S 40    // h_s stride (8 real coords + zeros to k=32)
#define GS_S 136   // g_s stride (128 channels + pad)

#define MFMA16(a,b,c) __builtin_amdgcn_mfma_f32_16x16x32_bf16((a),(b),(c),0,0,0)

static __device__ __forceinline__ f32x4 f4z(){ f32x4 v={0.f,0.f,0.f,0.f}; return v; }

// tau mapping: k-slot u=32ks+8lg+e <-> C-slot (mt=idx>>2, r=idx&3), idx=ks*8+e (valid idx<20)
// joint j = 16*mt + 4*lg + r. This makes P2's MFMA C-layout == P3's A-frag layout per lane.

__global__ __launch_bounds__(512, 4)
void ke_fused(const float* __restrict__ gx,  const float* __restrict__ gA,
              const float* __restrict__ gW1, const float* __restrict__ gg1, const float* __restrict__ gb1,
              const float* __restrict__ gW2, const float* __restrict__ gg2, const float* __restrict__ gb2,
              const float* __restrict__ gWp, const float* __restrict__ gbp,
              float* __restrict__ gout, int B)
{
  __shared__ __align__(16) bf16 A_lds[80*A_S];   // [n][u] = A[n][tau(u)]
  __shared__ __align__(16) bf16 x_t[16*XT_S];    // [coord][u] = x[tau(u)][coord]
  __shared__ __align__(16) bf16 h_s[80*HS_S];    // [j][k<8 coords, rest 0]
  __shared__ __align__(16) bf16 g_s[80*GS_S];    // [j][c]
  __shared__ __align__(16) float red_s[8*80];
  __shared__ __align__(16) float red_q[8*80];
  __shared__ __align__(16) float fin_mu[80];
  __shared__ __align__(16) float fin_rs[80];
  __shared__ __align__(16) float x_f32[228];
  __shared__ __align__(16) float skip_s[NH];
  __shared__ __align__(16) float g2b2[2*NH];
  __shared__ float xbar_s[4];

  const int tid = threadIdx.x;
  const int w   = tid >> 6;
  const int l   = tid & 63;
  const int l16 = l & 15;
  const int lg  = l >> 4;

  // ---------------- prologue (once) ----------------
  for (int i = tid; i < 16*XT_S; i += 512) x_t[i] = (bf16)0.f;
  for (int i = tid; i < 80*HS_S; i += 512) h_s[i] = (bf16)0.f;
  for (int i = tid; i < 80*A_S;  i += 512) {
    const int n = i / A_S, col = i - n*A_S;
    float v = 0.f;
    if (col < 96 && n < NJ) {
      const int ks = col >> 5, lgg = (col >> 3) & 3, e = col & 7;
      const int idx = ks*8 + e;
      if (idx < 20) {
        const int jk = ((idx>>2)<<4) + (lgg<<2) + (idx&3);
        if (jk < NJ) v = gA[n*NJ + jk];
      }
    }
    A_lds[i] = (bf16)v;
  }
  // W1 frag: channel c = 16w+l16, k = lg*8+e (coords, k>=3 zero)
  bf16x8 W1frag;
  {
    const int c = 16*w + l16;
    #pragma unroll
    for (int e = 0; e < 8; ++e) {
      const int k = lg*8 + e;
      W1frag[e] = (bf16)((k < 3) ? gW1[c*3 + k] : 0.f);
    }
  }
  // W2 frags: wave owns o in [32w, 32w+32)
  bf16x8 W2frag[2][4];
  #pragma unroll
  for (int m2 = 0; m2 < 2; ++m2) {
    const int o = 32*w + m2*16 + l16;
    #pragma unroll
    for (int ks = 0; ks < 4; ++ks) {
      const int c0 = ks*32 + lg*8;
      bf16x8 v;
      #pragma unroll
      for (int e = 0; e < 8; ++e) v[e] = (bf16)gW2[o*128 + c0 + e];
      W2frag[m2][ks] = v;
    }
  }
  const int cch = 16*w + l16;
  const float g1r = gg1[cch], b1r = gb1[cch];
  if (tid < NH) { g2b2[2*tid] = gg2[tid]; g2b2[2*tid+1] = gb2[tid]; }
  float wp0=0.f, wp1=0.f, wp2=0.f, bpr=0.f;
  if (tid < NH) { wp0 = gWp[tid*3]; wp1 = gWp[tid*3+1]; wp2 = gWp[tid*3+2]; bpr = gbp[tid]; }

  // x scatter index (tau^-1)
  int uix = 0, cc = 0;
  if (tid < 225) {
    const int jj = tid / 3; cc = tid - 3*jj;
    const int mt = jj >> 4, r = jj & 3, lgj = (jj >> 2) & 3;
    const int idx = 4*mt + r;
    uix = ((idx>>3)<<5) + (lgj<<3) + (idx&7);
  }
  __syncthreads();

  float xv = (tid < 225) ? gx[(size_t)blockIdx.x*225 + tid] : 0.f;

  // ---------------- frame loop ----------------
  for (int f = blockIdx.x; f < B; f += 512) {
    if (tid < 225) { x_f32[tid] = xv; x_t[cc*XT_S + uix] = (bf16)xv; }
    __syncthreads(); // b1
    { // prefetch next frame's x (hidden under this frame's compute)
      int fn = f + 512; if (fn >= B) fn = f;
      if (tid < 225) xv = gx[(size_t)fn*225 + tid];
    }

    // P1 (waves 0..4 only): h^T = x^T @ A, tile nt = w
    if (w < 5) {
      f32x4 acc = f4z();
      #pragma unroll
      for (int ks = 0; ks < 3; ++ks) {
        const bf16x8 xf = *(const bf16x8*)&x_t[l16*XT_S + ks*32 + lg*8];
        const bf16x8 af = *(const bf16x8*)&A_lds[(16*w + l16)*A_S + ks*32 + lg*8];
        acc = MFMA16(xf, af, acc);
      }
      if (lg < 2) {
        bf16x4 p;
        #pragma unroll
        for (int r = 0; r < 4; ++r) p[r] = (bf16)acc[r];
        *(bf16x4*)&h_s[(16*w + l16)*HS_S + lg*4] = p;
      }
    }
    // wave 7: xbar for skip
    if (w == 7) {
      float s0=0.f, s1=0.f, s2=0.f;
      if (l < NJ)      { s0  = x_f32[l*3];      s1  = x_f32[l*3+1];      s2  = x_f32[l*3+2]; }
      if (l + 64 < NJ) { s0 += x_f32[(l+64)*3]; s1 += x_f32[(l+64)*3+1]; s2 += x_f32[(l+64)*3+2]; }
      #pragma unroll
      for (int m = 32; m >= 1; m >>= 1) { s0 += __shfl_xor(s0,m); s1 += __shfl_xor(s1,m); s2 += __shfl_xor(s2,m); }
      if (l == 0) { xbar_s[0]=s0*(1.f/NJ); xbar_s[1]=s1*(1.f/NJ); xbar_s[2]=s2*(1.f/NJ); }
    }
    __syncthreads(); // b2

    // P2: h1pre = h @ W1^T, wave's 16 channels. acc1[mt]: j=16mt+4lg+r, c=16w+l16
    f32x4 acc1[5];
    #pragma unroll
    for (int mt = 0; mt < 5; ++mt) acc1[mt] = f4z();
    #pragma unroll
    for (int mt = 0; mt < 5; ++mt) {
      const bf16x8 hf = *(const bf16x8*)&h_s[(mt*16 + l16)*HS_S + lg*8];
      acc1[mt] = MFMA16(hf, W1frag, acc1[mt]);
    }
    // LN1 partials (over l16 = 16 channels)
    #pragma unroll
    for (int mt = 0; mt < 5; ++mt) {
      f32x4 sv = acc1[mt], qv;
      #pragma unroll
      for (int r = 0; r < 4; ++r) qv[r] = sv[r]*sv[r];
      #pragma unroll
      for (int m = 8; m >= 1; m >>= 1) {
        #pragma unroll
        for (int r = 0; r < 4; ++r) { sv[r] += __shfl_xor(sv[r], m); qv[r] += __shfl_xor(qv[r], m); }
      }
      if (l16 == 0) {
        *(f32x4*)&red_s[w*80 + mt*16 + lg*4] = sv;
        *(f32x4*)&red_q[w*80 + mt*16 + lg*4] = qv;
      }
    }
    __syncthreads(); // b3
    if (tid < 80) {
      float S=0.f, Q=0.f;
      #pragma unroll
      for (int ww = 0; ww < 8; ++ww) { S += red_s[ww*80 + tid]; Q += red_q[ww*80 + tid]; }
      const float mu = S * (1.f/128.f);
      const float var = Q * (1.f/128.f) - mu*mu;
      fin_mu[tid] = mu; fin_rs[tid] = rsqrtf(var + LN_EPS);
    }
    if (tid < NH) skip_s[tid] = bpr + wp0*xbar_s[0] + wp1*xbar_s[1] + wp2*xbar_s[2];
    __syncthreads(); // b4

    // LN1 apply + ReLU -> P3 A-frags directly in registers (tau layout match)
    bf16x8 paf[3];
    {
      float hv[5][4];
      #pragma unroll
      for (int mt = 0; mt < 5; ++mt) {
        const f32x4 mu4 = *(const f32x4*)&fin_mu[mt*16 + lg*4];
        const f32x4 rs4 = *(const f32x4*)&fin_rs[mt*16 + lg*4];
        #pragma unroll
        for (int r = 0; r < 4; ++r) {
          const float v = (acc1[mt][r] - mu4[r]) * rs4[r] * g1r + b1r;
          hv[mt][r] = fmaxf(v, 0.f);
        }
      }
      #pragma unroll
      for (int ks = 0; ks < 3; ++ks) {
        bf16x8 p;
        #pragma unroll
        for (int e = 0; e < 8; ++e) {
          const int idx = ks*8 + e;
          p[e] = (idx < 20) ? (bf16)hv[idx>>2][idx&3] : (bf16)0.f;
        }
        paf[ks] = p;
      }
    }

    // P3: g^T = h1^T @ A (reg A-op, LDS B-op). accg[nt]: c=16w+4lg+r rows, j=16nt+l16 cols
    f32x4 accg[5];
    #pragma unroll
    for (int nt = 0; nt < 5; ++nt) accg[nt] = f4z();
    #pragma unroll
    for (int ks = 0; ks < 3; ++ks) {
      #pragma unroll
      for (int nt = 0; nt < 5; ++nt) {
        const bf16x8 af = *(const bf16x8*)&A_lds[(nt*16 + l16)*A_S + ks*32 + lg*8];
        accg[nt] = MFMA16(paf[ks], af, accg[nt]);
      }
    }
    #pragma unroll
    for (int nt = 0; nt < 5; ++nt) {
      bf16x4 p;
      #pragma unroll
      for (int r = 0; r < 4; ++r) p[r] = (bf16)accg[nt][r];
      *(bf16x4*)&g_s[(nt*16 + l16)*GS_S + 16*w + lg*4] = p;
    }
    __syncthreads(); // b6

    // P4: z^T = W2 @ g^T, wave's 32 o
    f32x4 accz[5][2];
    #pragma unroll
    for (int nt = 0; nt < 5; ++nt) { accz[nt][0] = f4z(); accz[nt][1] = f4z(); }
    #pragma unroll
    for (int nt = 0; nt < 5; ++nt) {
      #pragma unroll
      for (int ks = 0; ks < 4; ++ks) {
        const bf16x8 gf = *(const bf16x8*)&g_s[(nt*16 + l16)*GS_S + ks*32 + lg*8];
        accz[nt][0] = MFMA16(W2frag[0][ks], gf, accz[nt][0]);
        accz[nt][1] = MFMA16(W2frag[1][ks], gf, accz[nt][1]);
      }
    }
    // LN2 partials (wave's 32 o: in-lane 8 + xor16 + xor32)
    #pragma unroll
    for (int nt = 0; nt < 5; ++nt) {
      float S = 0.f, Q = 0.f;
      #pragma unroll
      for (int m2 = 0; m2 < 2; ++m2)
        #pragma unroll
        for (int r = 0; r < 4; ++r) { const float v = accz[nt][m2][r]; S += v; Q += v*v; }
      S += __shfl_xor(S, 16); Q += __shfl_xor(Q, 16);
      S += __shfl_xor(S, 32); Q += __shfl_xor(Q, 32);
      if (lg == 0) { red_s[w*80 + nt*16 + l16] = S; red_q[w*80 + nt*16 + l16] = Q; }
    }
    __syncthreads(); // b7
    if (tid < 80) {
      float S=0.f, Q=0.f;
      #pragma unroll
      for (int ww = 0; ww < 8; ++ww) { S += red_s[ww*80 + tid]; Q += red_q[ww*80 + tid]; }
      const float mu = S * (1.f/256.f);
      const float var = Q * (1.f/256.f) - mu*mu;
      fin_mu[tid] = mu; fin_rs[tid] = rsqrtf(var + LN_EPS);
    }
    __syncthreads(); // b8

    // LN2 apply + ReLU + masked mean over j<75 + skip
    #pragma unroll
    for (int m2 = 0; m2 < 2; ++m2) {
      const int o0 = 32*w + m2*16 + lg*4;
      const f32x4 gb0  = *(const f32x4*)&g2b2[2*o0];
      const f32x4 gb1v = *(const f32x4*)&g2b2[2*o0 + 4];
      float os[4] = {0.f,0.f,0.f,0.f};
      #pragma unroll
      for (int nt = 0; nt < 5; ++nt) {
        const int j = nt*16 + l16;
        const float mu = fin_mu[j], rs = fin_rs[j];
        const bool jv = (nt < 4) || (l16 < 11);
        const float gg[4] = {gb0[0], gb0[2], gb1v[0], gb1v[2]};
        const float bb[4] = {gb0[1], gb0[3], gb1v[1], gb1v[3]};
        #pragma unroll
        for (int r = 0; r < 4; ++r) {
          float v = (accz[nt][m2][r] - mu) * rs * gg[r] + bb[r];
          v = fmaxf(v, 0.f);
          os[r] += jv ? v : 0.f;
        }
      }
      #pragma unroll
      for (int m = 8; m >= 1; m >>= 1) {
        #pragma unroll
        for (int r = 0; r < 4; ++r) os[r] += __shfl_xor(os[r], m);
      }
      if (l16 == 0) {
        const f32x4 sk = *(const f32x4*)&skip_s[o0];
        f32x4 res;
        #pragma unroll
        for (int r = 0; r < 4; ++r) res[r] = os[r]*(1.f/NJ) + sk[r];
        *(f32x4*)&gout[(size_t)f*NH + o0] = res;
      }
    }
  }
}

extern "C" void kernel_launch(void* const* d_in, const int* in_sizes, int n_in,
                              void* d_out, int out_size, void* d_ws, size_t ws_size,
                              hipStream_t stream) {
  const float* x  = (const float*)d_in[0];
  const float* A  = (const float*)d_in[1];
  const float* W1 = (const float*)d_in[2];
  const float* g1 = (const float*)d_in[3];
  const float* b1 = (const float*)d_in[4];
  const float* W2 = (const float*)d_in[5];
  const float* g2 = (const float*)d_in[6];
  const float* b2 = (const float*)d_in[7];
  const float* Wp = (const float*)d_in[8];
  const float* bp = (const float*)d_in[9];
  float* out = (float*)d_out;
  const int B = in_sizes[0] / 225;
  ke_fused<<<dim3(512), dim3(512), 0, stream>>>(x, A, W1, g1, b1, W2, g2, b2, Wp, bp, out, B);
}

// Round 4
// 334.022 us; speedup vs baseline: 1.5053x; 1.5053x over previous
//
#include <hip/hip_runtime.h>

typedef __bf16 bf16;
typedef __bf16 bf16x4 __attribute__((ext_vector_type(4)));
typedef __bf16 bf16x8 __attribute__((ext_vector_type(8)));
typedef float  f32x2  __attribute__((ext_vector_type(2)));
typedef float  f32x4  __attribute__((ext_vector_type(4)));
typedef unsigned int u32;
typedef u32 u32x4 __attribute__((ext_vector_type(4)));
typedef unsigned short u16;

#define NJ 75
#define STRH 104   // h1' [c][j'] stride (bf16): 96 slots + pad, 208B rows (16B-mult)
#define STRG 136   // g   [j][c] stride: 128 + pad, 272B rows (16B-mult)
#define STRX 104   // xT  [coord][j''] stride
#define LN_EPS 1e-5f
#define MFMA16(a,b,c) __builtin_amdgcn_mfma_f32_16x16x32_bf16((a),(b),(c),0,0,0)

static __device__ __forceinline__ f32x4 f4z(){ f32x4 v={0.f,0.f,0.f,0.f}; return v; }
static __device__ __forceinline__ float bperm(int srcLane, float v){
  return __int_as_float(__builtin_amdgcn_ds_bpermute(srcLane<<2, __float_as_int(v)));
}

__global__ __launch_bounds__(512, 2)
void ke3(const float* __restrict__ gx,  const float* __restrict__ gA,
         const float* __restrict__ gW1, const float* __restrict__ gg1, const float* __restrict__ gb1,
         const float* __restrict__ gW2, const float* __restrict__ gg2, const float* __restrict__ gb2,
         const float* __restrict__ gWp, const float* __restrict__ gbp,
         float* __restrict__ gout, int B)
{
  __shared__ __align__(16) bf16 h1s[2][128*STRH];  // h1' transposed [c][j'], dbuf
  __shared__ __align__(16) bf16 gss[2][80*STRG];   // g [j][c], dbuf
  __shared__ __align__(16) bf16 xTs[2][4*STRX];    // x^T [coord][j], dbuf
  __shared__ __align__(16) float reds[2][1280];    // LN2 partials [j][w][2]
  __shared__ __align__(16) float skl[4][256];      // skip per frame (4-deep)
  __shared__ __align__(16) u32  g1b1[128];         // packed bf16 (g1 lo, b1 hi)
  __shared__ float xbars[2][4];

  const int tid = threadIdx.x;
  const int w   = tid >> 6;
  const int l   = tid & 63;
  const int l16 = l & 15;
  const int lg  = l >> 4;

  // ---------------- one-time init ----------------
  {
    bf16* h1f = (bf16*)h1s;
    for (int t = tid; t < 2*128*STRH; t += 512) h1f[t] = (bf16)0.f;
    bf16* xtf = (bf16*)xTs;
    for (int t = tid; t < 2*4*STRX; t += 512) xtf[t] = (bf16)0.f;
  }
  if (tid < 128) {
    u32 a = (u32)__builtin_bit_cast(u16, (bf16)gg1[tid]);
    u32 b = (u32)__builtin_bit_cast(u16, (bf16)gb1[tid]);
    g1b1[tid] = a | (b << 16);
  }

  const int  fpb  = (B + 255) >> 8;           // frames per block (grid = 256)
  const long base = (long)blockIdx.x * fpb;

  // persistent fragments
  bf16x8 Afr[5][3];     // A[16jt+l16][32ks+8lg+e] (symmetric), zero-padded >=75
  #pragma unroll
  for (int jt = 0; jt < 5; ++jt) {
    const int row = 16*jt + l16;
    #pragma unroll
    for (int ks = 0; ks < 3; ++ks) {
      bf16x8 v;
      #pragma unroll
      for (int e = 0; e < 8; ++e) {
        const int col = 32*ks + 8*lg + e;
        v[e] = (bf16)((row < NJ && col < NJ) ? gA[row*NJ + col] : 0.f);
      }
      Afr[jt][ks] = v;
    }
  }
  bf16x8 W2fr[2][4];    // W2[o=16(2w+ot)+l16][c=32ks2+8lg+e]
  #pragma unroll
  for (int ot = 0; ot < 2; ++ot) {
    const int o = 16*(2*w + ot) + l16;
    #pragma unroll
    for (int ks = 0; ks < 4; ++ks) {
      bf16x8 v;
      #pragma unroll
      for (int e = 0; e < 8; ++e) v[e] = (bf16)gW2[o*128 + 32*ks + 8*lg + e];
      W2fr[ot][ks] = v;
    }
  }
  bf16x8 W1A[8];        // W1[c=16mt+l16][k] at e=0..2, junk elsewhere (killed by hfB zeros)
  #pragma unroll
  for (int mt = 0; mt < 8; ++mt) {
    const int c = 16*mt + l16;
    const float w0 = gW1[c*3], w1 = gW1[c*3+1], w2 = gW1[c*3+2];
    bf16x8 v;
    v[0] = (bf16)w0; v[1] = (bf16)w1; v[2] = (bf16)w2;
    v[3] = (bf16)w2; v[4] = (bf16)w2; v[5] = (bf16)w2; v[6] = (bf16)w2; v[7] = (bf16)w2;
    W1A[mt] = v;
  }
  float g2p[2][4], b2p[2][4];
  #pragma unroll
  for (int ot = 0; ot < 2; ++ot)
    #pragma unroll
    for (int r = 0; r < 4; ++r) {
      const int o = 16*(2*w + ot) + 4*lg + r;
      g2p[ot][r] = gg2[o]; b2p[ot][r] = gb2[o];
    }

  // prologue: stage frame 0 (slot 0) + xbar[0]  (wave 5)
  if (w == 5) {
    const long fc = (base < B) ? base : (long)(B-1);
    #pragma unroll
    for (int k = 0; k < 4; ++k) {
      const int t = l + 64*k;
      if (t < 225) {
        const float v = gx[fc*225 + t];
        const int j = (t*21846) >> 16;  // t/3
        const int co = t - 3*j;
        xTs[0][co*STRX + j] = (bf16)v;
      }
    }
    #pragma unroll
    for (int k = 0; k < 3; ++k) {
      float s = (float)xTs[0][k*STRX + l];
      if (l < 16) s += (float)xTs[0][k*STRX + 64 + l];
      #pragma unroll
      for (int m = 32; m >= 1; m >>= 1) s += __shfl_xor(s, m);
      if (l == 0) xbars[0][k] = s * (1.f/NJ);
    }
  }
  __syncthreads();

  f32x4 zacc[5][2];   // z tile, persists across one barrier
  #pragma unroll
  for (int jt = 0; jt < 5; ++jt) { zacc[jt][0] = f4z(); zacc[jt][1] = f4z(); }

  const int nint = fpb + 3;
  for (int i = 0; i < nint; ++i) {
    // ================= S_A: frame i (waves 0-4) / S_X wave5 / S_SK wave6 =================
    if (i < fpb) {
      if (w < 5) {
        // hT = x^T A (own j-tile)
        f32x4 at = f4z();
        const int xrow = (l16 < 3) ? l16 : 3;
        const bf16* xb = &xTs[i&1][xrow*STRX];
        #pragma unroll
        for (int ks = 0; ks < 3; ++ks)
          at = MFMA16(*(const bf16x8*)&xb[32*ks + 8*lg], Afr[w][ks], at);
        // build hfB: col l16 = own j, k=coord at lg0/e<3, zeros elsewhere
        bf16x8 hfB;
        #pragma unroll
        for (int e = 0; e < 8; ++e) hfB[e] = (bf16)0.f;
        {
          const float a0 = (lg == 0) ? at[0] : 0.f;
          const float a1 = (lg == 0) ? at[1] : 0.f;
          const float a2 = (lg == 0) ? at[2] : 0.f;
          hfB[0] = (bf16)a0; hfB[1] = (bf16)a1; hfB[2] = (bf16)a2;
        }
        // h1pre^T = W1 (x) hfB : rows c, col own-j
        f32x4 hp[8];
        #pragma unroll
        for (int mt = 0; mt < 8; ++mt) hp[mt] = MFMA16(W1A[mt], hfB, f4z());
        // LN1 (stats over c: in-reg + lg-xor)
        float s = 0.f, q = 0.f;
        #pragma unroll
        for (int mt = 0; mt < 8; ++mt)
          #pragma unroll
          for (int r = 0; r < 4; ++r) { const float v = hp[mt][r]; s += v; q = fmaf(v, v, q); }
        s += __shfl_xor(s, 16); s += __shfl_xor(s, 32);
        q += __shfl_xor(q, 16); q += __shfl_xor(q, 32);
        const float mu = s * (1.f/128.f);
        const float rs = rsqrtf(q * (1.f/128.f) - mu*mu + LN_EPS);
        const float nm = -mu * rs;
        bf16* hw = &h1s[i&1][0];
        const int jcol = 16*w + l16;
        #pragma unroll
        for (int mt = 0; mt < 8; ++mt) {
          const u32x4 gb = *(const u32x4*)&g1b1[16*mt + 4*lg];
          #pragma unroll
          for (int r = 0; r < 4; ++r) {
            const float gam = __uint_as_float(gb[r] << 16);
            const float bet = __uint_as_float(gb[r] & 0xffff0000u);
            float v = fmaf(hp[mt][r], rs, nm);
            v = fmaf(v, gam, bet);
            v = fmaxf(v, 0.f);
            hw[(16*mt + 4*lg + r)*STRH + jcol] = (bf16)v;
          }
        }
      } else if (w == 5) {
        // stage x for frame i+1
        if (i + 1 < fpb) {
          const int slot = (i+1) & 1;
          long fg = base + i + 1; if (fg >= B) fg = B - 1;
          #pragma unroll
          for (int k = 0; k < 4; ++k) {
            const int t = l + 64*k;
            if (t < 225) {
              const float v = gx[fg*225 + t];
              const int j = (t*21846) >> 16;
              const int co = t - 3*j;
              xTs[slot][co*STRX + j] = (bf16)v;
            }
          }
          #pragma unroll
          for (int k = 0; k < 3; ++k) {
            float s = (float)xTs[slot][k*STRX + l];
            if (l < 16) s += (float)xTs[slot][k*STRX + 64 + l];
            #pragma unroll
            for (int m = 32; m >= 1; m >>= 1) s += __shfl_xor(s, m);
            if (l == 0) xbars[slot][k] = s * (1.f/NJ);
          }
        }
      } else if (w == 6) {
        // skip(i) = bp + Wp . xbar(i)
        const float xb0 = xbars[i&1][0], xb1 = xbars[i&1][1], xb2 = xbars[i&1][2];
        #pragma unroll
        for (int k = 0; k < 4; ++k) {
          const int o = l + 64*k;
          const float v = gbp[o] + gWp[o*3]*xb0 + gWp[o*3+1]*xb1 + gWp[o*3+2]*xb2;
          skl[i&3][o] = v;
        }
      }
    }

    // ================= S_B: frame i-1, g = A h1' (c-sliced, all 8 waves) =================
    if (i >= 1 && i-1 < fpb) {
      const bf16* hb = &h1s[(i-1)&1][(16*w + l16)*STRH];
      bf16x8 hf[3];
      #pragma unroll
      for (int ks = 0; ks < 3; ++ks) hf[ks] = *(const bf16x8*)&hb[32*ks + 8*lg];
      bf16* go = &gss[(i-1)&1][0];
      #pragma unroll
      for (int jt = 0; jt < 5; ++jt) {
        f32x4 ag = f4z();
        #pragma unroll
        for (int ks = 0; ks < 3; ++ks) ag = MFMA16(hf[ks], Afr[jt][ks], ag);
        bf16x4 p;
        #pragma unroll
        for (int r = 0; r < 4; ++r) p[r] = (bf16)ag[r];
        *(bf16x4*)&go[(16*jt + l16)*STRG + 16*w + 4*lg] = p;
      }
    }

    // ================= S_D: frame i-3, LN2 + mean + skip + store (consumes zacc) =========
    if (i >= 3 && i-3 < fpb) {
      const int sD = (i-1)&1;
      // finalize stats (redundant per wave): lane l -> j=l ; lanes<16 also j=64+l
      const float* rp = &reds[sD][l*16];
      const f32x4 r0 = *(const f32x4*)&rp[0];
      const f32x4 r1 = *(const f32x4*)&rp[4];
      const f32x4 r2 = *(const f32x4*)&rp[8];
      const f32x4 r3 = *(const f32x4*)&rp[12];
      const float S  = r0[0]+r0[2]+r1[0]+r1[2]+r2[0]+r2[2]+r3[0]+r3[2];
      const float Q  = r0[1]+r0[3]+r1[1]+r1[3]+r2[1]+r2[3]+r3[1]+r3[3];
      const float mu = S * (1.f/256.f);
      const float rs = rsqrtf(Q * (1.f/256.f) - mu*mu + LN_EPS);
      const float nm = -mu * rs;
      float rs2 = 0.f, nm2 = 0.f;
      if (l < 16) {
        const float* rp2 = &reds[sD][(64 + l)*16];
        const f32x4 s0 = *(const f32x4*)&rp2[0];
        const f32x4 s1 = *(const f32x4*)&rp2[4];
        const f32x4 s2 = *(const f32x4*)&rp2[8];
        const f32x4 s3 = *(const f32x4*)&rp2[12];
        const float S2 = s0[0]+s0[2]+s1[0]+s1[2]+s2[0]+s2[2]+s3[0]+s3[2];
        const float Q2 = s0[1]+s0[3]+s1[1]+s1[3]+s2[1]+s2[3]+s3[1]+s3[3];
        const float m2 = S2 * (1.f/256.f);
        rs2 = rsqrtf(Q2 * (1.f/256.f) - m2*m2 + LN_EPS);
        nm2 = -m2 * rs2;
      }
      float rsv[5], nmv[5];
      #pragma unroll
      for (int jt = 0; jt < 4; ++jt) {
        rsv[jt] = bperm(16*jt + l16, rs);
        nmv[jt] = bperm(16*jt + l16, nm);
      }
      rsv[4] = bperm(l16, rs2);
      nmv[4] = bperm(l16, nm2);
      // apply + relu + mask + sum over j
      float os[2][4];
      #pragma unroll
      for (int ot = 0; ot < 2; ++ot)
        #pragma unroll
        for (int r = 0; r < 4; ++r) os[ot][r] = 0.f;
      #pragma unroll
      for (int jt = 0; jt < 5; ++jt)
        #pragma unroll
        for (int ot = 0; ot < 2; ++ot)
          #pragma unroll
          for (int r = 0; r < 4; ++r) {
            float u = fmaf(zacc[jt][ot][r], rsv[jt], nmv[jt]);
            float v = fmaf(u, g2p[ot][r], b2p[ot][r]);
            v = fmaxf(v, 0.f);
            if (jt == 4) v = (l16 < 11) ? v : 0.f;
            os[ot][r] += v;
          }
      #pragma unroll
      for (int m = 8; m >= 1; m >>= 1)
        #pragma unroll
        for (int ot = 0; ot < 2; ++ot)
          #pragma unroll
          for (int r = 0; r < 4; ++r) os[ot][r] += __shfl_xor(os[ot][r], m);
      if (l16 == 0) {
        const long f = base + (i-3);
        if (f < B) {
          #pragma unroll
          for (int ot = 0; ot < 2; ++ot) {
            const int o0 = 16*(2*w + ot) + 4*lg;
            const f32x4 sk = *(const f32x4*)&skl[(i-3)&3][o0];
            f32x4 res;
            #pragma unroll
            for (int r = 0; r < 4; ++r) res[r] = os[ot][r] * (1.f/NJ) + sk[r];
            *(f32x4*)&gout[f*256 + o0] = res;
          }
        }
      }
    }

    // ================= S_C: frame i-2, z = W2 g^T (o-sliced) + stats ====================
    if (i >= 2 && i-2 < fpb) {
      #pragma unroll
      for (int jt = 0; jt < 5; ++jt) { zacc[jt][0] = f4z(); zacc[jt][1] = f4z(); }
      const bf16* gp = &gss[i&1][0];
      #pragma unroll
      for (int jt = 0; jt < 5; ++jt) {
        const bf16* gr = &gp[(16*jt + l16)*STRG + 8*lg];
        bf16x8 gf[4];
        #pragma unroll
        for (int ks = 0; ks < 4; ++ks) gf[ks] = *(const bf16x8*)&gr[32*ks];
        #pragma unroll
        for (int ks = 0; ks < 4; ++ks) {
          zacc[jt][0] = MFMA16(W2fr[0][ks], gf[ks], zacc[jt][0]);
          zacc[jt][1] = MFMA16(W2fr[1][ks], gf[ks], zacc[jt][1]);
        }
      }
      #pragma unroll
      for (int jt = 0; jt < 5; ++jt) {
        float s = 0.f, q = 0.f;
        #pragma unroll
        for (int ot = 0; ot < 2; ++ot)
          #pragma unroll
          for (int r = 0; r < 4; ++r) { const float v = zacc[jt][ot][r]; s += v; q = fmaf(v, v, q); }
        s += __shfl_xor(s, 16); s += __shfl_xor(s, 32);
        q += __shfl_xor(q, 16); q += __shfl_xor(q, 32);
        if (lg == 0) {
          f32x2 sq = {s, q};
          *(f32x2*)&reds[i&1][(16*jt + l16)*16 + w*2] = sq;
        }
      }
    }

    __syncthreads();
  }
}

extern "C" void kernel_launch(void* const* d_in, const int* in_sizes, int n_in,
                              void* d_out, int out_size, void* d_ws, size_t ws_size,
                              hipStream_t stream) {
  const float* x  = (const float*)d_in[0];
  const float* A  = (const float*)d_in[1];
  const float* W1 = (const float*)d_in[2];
  const float* g1 = (const float*)d_in[3];
  const float* b1 = (const float*)d_in[4];
  const float* W2 = (const float*)d_in[5];
  const float* g2 = (const float*)d_in[6];
  const float* b2 = (const float*)d_in[7];
  const float* Wp = (const float*)d_in[8];
  const float* bp = (const float*)d_in[9];
  float* out = (float*)d_out;
  const int B = in_sizes[0] / 225;
  ke3<<<dim3(256), dim3(512), 0, stream>>>(x, A, W1, g1, b1, W2, g2, b2, Wp, bp, out, B);
}